// Round 13
// baseline (104.999 us; speedup 1.0000x reference)
//
#include <hip/hip_runtime.h>
#include <math.h>

#define BLOCK 256
#define PPT 8               // rows per thread -> 2048 rows per block
#define RPB (BLOCK * PPT)   // 2048
#define CGROUP 64           // cols per register buffer (one col per lane)
#define CGROUPS 2           // groups per block -> 128 cols per block
#define RTILE 16            // cols per scmin reduce chunk
#define SPAD 257            // scmin padded stride (bank = (c+i)%32, conflict-free)
#define FBLOCKS 128

// ---- order-preserving float <-> uint key (works for negatives) ----
__device__ __forceinline__ unsigned f2key(float f) {
    unsigned b = __float_as_uint(f);
    return b ^ ((b & 0x80000000u) ? 0xFFFFFFFFu : 0x80000000u);
}
__device__ __forceinline__ float key2f(unsigned k) {
    unsigned b = k ^ ((k & 0x80000000u) ? 0x80000000u : 0xFFFFFFFFu);
    return __uint_as_float(b);
}
__device__ __forceinline__ float min3f(float a, float b, float c) {
    return fminf(fminf(a, b), c);   // -> v_min3_f32
}
// wave-broadcast: lane l's value -> SGPR (uniform). VALU 1-slot, no memory.
__device__ __forceinline__ float rlane(float v, int l) {
    return __int_as_float(__builtin_amdgcn_readlane(__float_as_int(v), l));
}

// R13: LDS-free inner loop. Col points live IN LANES (lane l of every wave
// holds the prescaled quad (-2x,-2y,-2z,|b|^2) of col l of the current
// 64-col group, loaded once per group). Per 2-col step, 8 v_readlane
// broadcasts move the two cols into SGPRs; v_fma/v_add take 1 SGPR operand
// free -> the main loop issues ZERO ds_read and has no staging barriers.
// This is the decisive test of whether the inner-loop ds_read_b128 (and its
// compiler-planted waitcnt) was the residual binder: R4/R6/R7/R10/R12 showed
// time invariant to LDS traffic, SW pipelining, and occupancy (2/4/8 blk/CU).
//   - row mins (dist1): register accumulators, ONE atomicMin per row per block
//   - col mins (dist2): per-thread min3-fold -> scmin[col][tid] (ds_write
//     only), block tree-reduce per 16-col chunk, one atomicMin per col
__global__ __launch_bounds__(BLOCK) void chamfer_tile_kernel(
    const float* __restrict__ arr1, const float* __restrict__ arr2,
    int N, int M,
    unsigned* __restrict__ rkey, unsigned* __restrict__ ckey,
    float* __restrict__ out)
{
    const int b    = blockIdx.z;
    const int r0   = blockIdx.x * RPB;                 // row offset in batch
    const int c0   = blockIdx.y * (CGROUP * CGROUPS);  // col offset in batch
    const int lane = threadIdx.x & 63;

    // Zero the output accumulator exactly once (finalize is a later dispatch).
    if (blockIdx.x == 0 && blockIdx.y == 0 && blockIdx.z == 0 && threadIdx.x == 0)
        out[0] = 0.0f;

    __shared__ float scmin[RTILE][SPAD];
    __shared__ float cred[16][RTILE];

    // Row points in registers (+ their squared norms)
    float ax[PPT], ay[PPT], az[PPT], a2[PPT], mn[PPT];
    const float* abase = arr1 + ((size_t)b * N + r0) * 3;
#pragma unroll
    for (int k = 0; k < PPT; ++k) {
        int idx = threadIdx.x + k * BLOCK;
        float x = abase[idx * 3 + 0];
        float y = abase[idx * 3 + 1];
        float z = abase[idx * 3 + 2];
        ax[k] = x; ay[k] = y; az[k] = z;
        a2[k] = __builtin_fmaf(x, x, __builtin_fmaf(y, y, z * z));
        mn[k] = __builtin_inff();
    }

    // Load group 0's col quad: lane l holds col (c0+l), prescaled.
    float bx, by, bz, bw;
    {
        const float* p = arr2 + ((size_t)b * M + c0 + lane) * 3;
        float x = p[0], y = p[1], z = p[2];
        bx = -2.0f * x; by = -2.0f * y; bz = -2.0f * z;
        bw = __builtin_fmaf(x, x, __builtin_fmaf(y, y, z * z));
    }

#pragma unroll 1
    for (int g = 0; g < CGROUPS; ++g) {
        // Prefetch next group's quad while computing on the current one.
        float nx = 0.f, ny = 0.f, nz = 0.f, nw = 0.f;
        if (g + 1 < CGROUPS) {
            const float* p = arr2 + ((size_t)b * M + c0 + (g + 1) * CGROUP + lane) * 3;
            float x = p[0], y = p[1], z = p[2];
            nx = -2.0f * x; ny = -2.0f * y; nz = -2.0f * z;
            nw = __builtin_fmaf(x, x, __builtin_fmaf(y, y, z * z));
        }
        const int cg = c0 + g * CGROUP;

#pragma unroll 1
        for (int sub = 0; sub < CGROUP / RTILE; ++sub) {
#pragma unroll 1
            for (int jj = 0; jj < RTILE; jj += 2) {
                const int l0 = sub * RTILE + jj;
                // Broadcast 2 cols to SGPRs (dynamic-uniform lane index OK)
                float s0x = rlane(bx, l0),     s0y = rlane(by, l0);
                float s0z = rlane(bz, l0),     s0w = rlane(bw, l0);
                float s1x = rlane(bx, l0 + 1), s1y = rlane(by, l0 + 1);
                float s1z = rlane(bz, l0 + 1), s1w = rlane(bw, l0 + 1);
                float d0a[PPT], d1a[PPT];
#pragma unroll
                for (int k = 0; k < PPT; ++k) {
                    float t0 = a2[k] + s0w;
                    float t1 = a2[k] + s1w;
                    float d0 = __builtin_fmaf(s0x, ax[k],
                               __builtin_fmaf(s0y, ay[k],
                               __builtin_fmaf(s0z, az[k], t0)));
                    float d1 = __builtin_fmaf(s1x, ax[k],
                               __builtin_fmaf(s1y, ay[k],
                               __builtin_fmaf(s1z, az[k], t1)));
                    mn[k] = min3f(mn[k], d0, d1);   // row min
                    d0a[k] = d0;
                    d1a[k] = d1;
                }
                // Col partial: min3-fold this thread's 8 rows per col
                float cm0 = fminf(min3f(min3f(min3f(d0a[0], d0a[1], d0a[2]),
                                              d0a[3], d0a[4]),
                                        d0a[5], d0a[6]),
                                  d0a[7]);
                float cm1 = fminf(min3f(min3f(min3f(d1a[0], d1a[1], d1a[2]),
                                              d1a[3], d1a[4]),
                                        d1a[5], d1a[6]),
                                  d1a[7]);
                scmin[jj][threadIdx.x]     = cm0;   // bank (jj+tid)%32: 2-way
                scmin[jj + 1][threadIdx.x] = cm1;
            }
            __syncthreads();

            // Col reduce stage 1: thread (cc = tid&15, s = tid>>4) tree-reduces
            // scmin[cc][s*16 .. s*16+15]. bank = (cc+16s+i)%32 -> 2-way, free.
            {
                int cc = threadIdx.x & 15, s = threadIdx.x >> 4;
                const float* row = &scmin[cc][s * 16];
                float v0 = row[0], v1 = row[1];
#pragma unroll
                for (int i = 2; i < 16; i += 2) {
                    v0 = fminf(v0, row[i]);
                    v1 = fminf(v1, row[i + 1]);
                }
                cred[s][cc] = fminf(v0, v1);
            }
            __syncthreads();
            // Stage 2: 16 threads fold the 16 segment partials, 1 atomic/col.
            if (threadIdx.x < RTILE) {
                float v0 = cred[0][threadIdx.x], v1 = cred[1][threadIdx.x];
#pragma unroll
                for (int s = 2; s < 16; s += 2) {
                    v0 = fminf(v0, cred[s][threadIdx.x]);
                    v1 = fminf(v1, cred[s + 1][threadIdx.x]);
                }
                atomicMin(&ckey[(size_t)b * M + cg + sub * RTILE + threadIdx.x],
                          f2key(fminf(v0, v1)));
            }
        }

        bx = nx; by = ny; bz = nz; bw = nw;
    }

    // Row partials -> ONE atomicMin per row per block (after all col groups)
    unsigned* rk = rkey + (size_t)b * N + r0;
#pragma unroll
    for (int k = 0; k < PPT; ++k)
        atomicMin(&rk[threadIdx.x + k * BLOCK], f2key(mn[k]));
}

// Finalize: keys already hold full d mins (a^2 and b^2 included) -> just a
// weighted sum of 64k values (0.26 MB), one atomicAdd per block.
__global__ __launch_bounds__(256) void chamfer_finalize_kernel(
    const unsigned* __restrict__ rkey, const unsigned* __restrict__ ckey,
    int BN, int BM, float* __restrict__ out)
{
    const float wA = 1.0f / (float)BN;
    const float wB = 1.0f / (float)BM;
    const int stride = 256 * FBLOCKS;

    float s = 0.0f;
    for (int i = blockIdx.x * 256 + threadIdx.x; i < BN; i += stride)
        s += wA * key2f(rkey[i]);
    for (int i = blockIdx.x * 256 + threadIdx.x; i < BM; i += stride)
        s += wB * key2f(ckey[i]);

#pragma unroll
    for (int off = 32; off > 0; off >>= 1)
        s += __shfl_down(s, off, 64);

    __shared__ float wsum[4];
    int lane = threadIdx.x & 63, wv = threadIdx.x >> 6;
    if (lane == 0) wsum[wv] = s;
    __syncthreads();
    if (threadIdx.x == 0)
        atomicAdd(out, wsum[0] + wsum[1] + wsum[2] + wsum[3]);
}

extern "C" void kernel_launch(void* const* d_in, const int* in_sizes, int n_in,
                              void* d_out, int out_size, void* d_ws, size_t ws_size,
                              hipStream_t stream)
{
    const float* arr1 = (const float*)d_in[0];
    const float* arr2 = (const float*)d_in[1];
    float* out = (float*)d_out;

    const int Bb = 4;
    const int N = in_sizes[0] / (Bb * 3);   // 8192
    const int M = in_sizes[1] / (Bb * 3);   // 8192
    const int BN = Bb * N, BM = Bb * M;

    unsigned* rkey = (unsigned*)d_ws;        // [BN]
    unsigned* ckey = rkey + BN;              // [BM]

    // Init all min-keys to 0xFFFFFFFF (max) — ws is poisoned 0xAA each launch.
    hipMemsetAsync(rkey, 0xFF, (size_t)(BN + BM) * sizeof(unsigned), stream);

    dim3 grid(N / RPB, M / (CGROUP * CGROUPS), Bb);   // (4, 64, 4) = 1024
    chamfer_tile_kernel<<<grid, BLOCK, 0, stream>>>(arr1, arr2, N, M,
                                                    rkey, ckey, out);

    chamfer_finalize_kernel<<<FBLOCKS, 256, 0, stream>>>(rkey, ckey, BN, BM, out);
}